// Round 1
// 159.980 us; speedup vs baseline: 1.0170x; 1.0170x over previous
//
#include <hip/hip_runtime.h>

// LinearAttention: B=2, L=2048, D=1024, H=16, d=64.
// cvt_all ; QKV GEMM (NEW: 256^2 8-phase) ; kv_local ; kv_prefix ; attn_chunk ; out GEMM.
// R6: QKV GEMM moved from m97-structure (128^2, BK=32, full-drain barriers, 596 TF)
// to the 8-phase 256^2 template: BK=64 dbuf, raw s_barrier (no implicit vmcnt
// drain), counted staging with vmcnt(0) only twice per 8 phases (each covered by
// >=1.5 MFMA phases), T2 both-sides XOR swizzle (pre-swizzled global src +
// swizzled ds_read), T1 XCD block swizzle, T5 setprio around MFMA clusters.

#define DEV __device__ __forceinline__

typedef __attribute__((ext_vector_type(8))) short bf16x8;
typedef __attribute__((ext_vector_type(4))) float f32x4;

DEV ushort f2bf(float f) {
  union { float f; unsigned u; } v; v.f = f;
  unsigned r = v.u + 0x7fffu + ((v.u >> 16) & 1u);
  return (ushort)(r >> 16);
}
DEV float bf2f(unsigned b) {
  union { unsigned u; float f; } v; v.u = (b & 0xffffu) << 16;
  return v.f;
}
DEV void glds16(const ushort* g, ushort* l) {
  __builtin_amdgcn_global_load_lds(
      (const __attribute__((address_space(1))) unsigned int*)g,
      (__attribute__((address_space(3))) unsigned int*)l, 16, 0, 0);
}

__global__ __launch_bounds__(256) void cvt_all(const float* __restrict__ x,
                                               const float* __restrict__ Ww,
                                               const float* __restrict__ Ow,
                                               ushort* __restrict__ xb,
                                               ushort* __restrict__ wqkvb,
                                               ushort* __restrict__ outwb) {
  int i = blockIdx.x * 256 + threadIdx.x;
  const float* src; ushort* dst; int off;
  if (i < 1048576)      { src = x;  dst = xb;    off = i; }
  else if (i < 1835008) { src = Ww; dst = wqkvb; off = i - 1048576; }
  else                  { src = Ow; dst = outwb; off = i - 1835008; }
  float4 v = ((const float4*)src)[off];
  ushort4 o;
  o.x = f2bf(v.x); o.y = f2bf(v.y); o.z = f2bf(v.z); o.w = f2bf(v.w);
  ((ushort4*)dst)[off] = o;
}

// ---------------------------------------------------------------------------
// 8-phase 256x256 GEMM: C = A[M,K]*Bw[N,K]^T + bias.
// 512 threads = 8 waves (2M x 4N). Per-wave output 128x64 (8x4 fragments).
// BK=64 (2 k-slices per tile), double-buffered LDS 128 KiB.
// Schedule per tile-pair (8 phases):
//   phases 1-4: compute tile 2i (buf0), stage tile 2i+1 -> buf1 (A@p1, B0@p2, B1@p3)
//   phase  4  : vmcnt(0) before barrier2 (drains 2i+1; issued >=1 phase earlier)
//   phases 5-8: compute tile 2i+1 (buf1), stage tile 2i+2 -> buf0
//   phase  8  : vmcnt(0) before barrier2 (drains 2i+2)
// Safety: buf1 overwrite issued after prior iter's phase-8 barrier (its reads
// were consumed by phase-8 MFMAs); buf0 overwrite issued after phase-4 barrier.
// T2 swizzle: logical 16B col-block c of row r stored at physical c^(r&7);
// glds dest stays linear, global source column pre-swizzled (rule #21).
// ---------------------------------------------------------------------------
template <bool OUT_BF16, bool KSCALE>
__global__ __launch_bounds__(512, 2) void gemm_bt8(const ushort* __restrict__ A,
                                                   const ushort* __restrict__ Bw,
                                                   const float* __restrict__ bias,
                                                   void* __restrict__ Cout,
                                                   int M, int N, int K) {
  __shared__ __align__(16) ushort As[2][16384];
  __shared__ __align__(16) ushort Bs[2][16384];
  const int t = threadIdx.x;
  const int lane = t & 63, wid = t >> 6;
  const int quad = lane >> 4, l16 = lane & 15;
  const int wm2 = wid >> 2, wn4 = wid & 3;

  // T1: bijective XCD swizzle (gridDim.x % 8 == 0).
  const int nwg = gridDim.x;
  const int bid = blockIdx.x;
  const int wg = (bid & 7) * (nwg >> 3) + (bid >> 3);
  const int nbx = N >> 8;
  const int bx = wg % nbx, by = wg / nbx;
  const int bm = by << 8, bn = bx << 8;

  // staging: thread t covers row srow of a 64-row half-call, 16B at swizzled col.
  const int srow = t >> 3;                        // 0..63
  const int scol = ((t & 7) ^ (srow & 7)) << 3;   // pre-swizzled k-offset (ushorts)
  const ushort* ag = A + (size_t)(bm + srow) * K + scol;
  const ushort* bg = Bw + (size_t)(bn + srow) * K + scol;
  const int NT = K >> 6;  // K-tiles of 64

  f32x4 acc[8][4];
  const f32x4 z = {0.f, 0.f, 0.f, 0.f};
#pragma unroll
  for (int i = 0; i < 8; ++i)
#pragma unroll
    for (int j = 0; j < 4; ++j) acc[i][j] = z;

  const int aRow = wm2 * 128 + l16;  // + mi*16
  const int bRow = wn4 * 64 + l16;   // + nj*16
  const int cxor = l16 & 7;

#define SG_A(bufi, kt, h, j) \
  glds16(ag + (size_t)((h)*128 + (j)*64) * K + ((kt) << 6), \
         &As[bufi][(h)*8192 + (j)*4096 + wid * 512])
#define SG_B(bufi, kt, h, j) \
  glds16(bg + (size_t)((h)*128 + (j)*64) * K + ((kt) << 6), \
         &Bs[bufi][(h)*8192 + (j)*4096 + wid * 512])
#define RD_A(bufi, mi, kc) \
  (*(const bf16x8*)&As[bufi][(aRow + (mi)*16) * 64 + ((((kc)*4 + quad) ^ cxor) << 3)])
#define RD_B(bufi, nj, kc) \
  (*(const bf16x8*)&Bs[bufi][(bRow + (nj)*16) * 64 + ((((kc)*4 + quad) ^ cxor) << 3)])

  // prologue: tile 0 -> buf0
  SG_A(0, 0, 0, 0); SG_A(0, 0, 0, 1); SG_A(0, 0, 1, 0); SG_A(0, 0, 1, 1);
  SG_B(0, 0, 0, 0); SG_B(0, 0, 0, 1); SG_B(0, 0, 1, 0); SG_B(0, 0, 1, 1);
  asm volatile("s_waitcnt vmcnt(0)" ::: "memory");
  __builtin_amdgcn_s_barrier();

  bf16x8 bf[4][2], af[2][2];

#define LOAD_AF(rb, mi0) \
  af[0][0] = RD_A(rb, (mi0), 0); af[0][1] = RD_A(rb, (mi0), 1); \
  af[1][0] = RD_A(rb, (mi0) + 1, 0); af[1][1] = RD_A(rb, (mi0) + 1, 1);

#define MFMA16(mi0) \
  __builtin_amdgcn_s_setprio(1); \
  _Pragma("unroll") \
  for (int nj = 0; nj < 4; ++nj) { \
    acc[(mi0)][nj] = __builtin_amdgcn_mfma_f32_16x16x32_bf16(af[0][0], bf[nj][0], acc[(mi0)][nj], 0, 0, 0); \
    acc[(mi0)][nj] = __builtin_amdgcn_mfma_f32_16x16x32_bf16(af[0][1], bf[nj][1], acc[(mi0)][nj], 0, 0, 0); \
    acc[(mi0) + 1][nj] = __builtin_amdgcn_mfma_f32_16x16x32_bf16(af[1][0], bf[nj][0], acc[(mi0) + 1][nj], 0, 0, 0); \
    acc[(mi0) + 1][nj] = __builtin_amdgcn_mfma_f32_16x16x32_bf16(af[1][1], bf[nj][1], acc[(mi0) + 1][nj], 0, 0, 0); \
  } \
  __builtin_amdgcn_s_setprio(0);

#define HALFSTEP(rb, sb, stTile, doSt) do { \
    /* phase A: stage A-halves of next tile; read all B frags + A frags 0,1 */ \
    if (doSt) { SG_A(sb, stTile, 0, 0); SG_A(sb, stTile, 0, 1); \
                SG_A(sb, stTile, 1, 0); SG_A(sb, stTile, 1, 1); } \
    _Pragma("unroll") \
    for (int nj = 0; nj < 4; ++nj) { bf[nj][0] = RD_B(rb, nj, 0); bf[nj][1] = RD_B(rb, nj, 1); } \
    LOAD_AF(rb, 0); \
    __builtin_amdgcn_s_barrier(); \
    MFMA16(0); \
    __builtin_amdgcn_s_barrier(); \
    /* phase B */ \
    if (doSt) { SG_B(sb, stTile, 0, 0); SG_B(sb, stTile, 0, 1); } \
    LOAD_AF(rb, 2); \
    __builtin_amdgcn_s_barrier(); \
    MFMA16(2); \
    __builtin_amdgcn_s_barrier(); \
    /* phase C */ \
    if (doSt) { SG_B(sb, stTile, 1, 0); SG_B(sb, stTile, 1, 1); } \
    LOAD_AF(rb, 4); \
    __builtin_amdgcn_s_barrier(); \
    MFMA16(4); \
    __builtin_amdgcn_s_barrier(); \
    /* phase D: drain staging so the other buffer is ready after barrier2 */ \
    LOAD_AF(rb, 6); \
    __builtin_amdgcn_s_barrier(); \
    MFMA16(6); \
    asm volatile("s_waitcnt vmcnt(0)" ::: "memory"); \
    __builtin_amdgcn_s_barrier(); \
  } while (0)

  const int half = NT >> 1;
  for (int i = 0; i < half; ++i) {
    HALFSTEP(0, 1, 2 * i + 1, true);             // compute tile 2i, stage 2i+1
    HALFSTEP(1, 0, 2 * i + 2, (i < half - 1));   // compute tile 2i+1, stage 2i+2
  }

#undef HALFSTEP
#undef MFMA16
#undef LOAD_AF
#undef RD_A
#undef RD_B
#undef SG_A
#undef SG_B

#pragma unroll
  for (int mi = 0; mi < 8; ++mi)
#pragma unroll
    for (int nj = 0; nj < 4; ++nj) {
      const int col = bn + wn4 * 64 + nj * 16 + l16;
      const float bv = bias[col];
      float sc = 1.f;
      if (KSCALE) sc = ((col >> 10) == 1) ? 0.125f : 1.f;
#pragma unroll
      for (int r = 0; r < 4; ++r) {
        const int row = bm + wm2 * 128 + mi * 16 + quad * 4 + r;
        const float v = (acc[mi][nj][r] + bv) * sc;
        if (OUT_BF16)
          ((ushort*)Cout)[(size_t)row * N + col] = f2bf(v);
        else
          ((float*)Cout)[(size_t)row * N + col] = v;
      }
    }
}

// Out projection: BM=64, BN=128, BK=32 -> 512 blocks (2/CU), identity staging.
__global__ __launch_bounds__(256) void gemm_out64(const ushort* __restrict__ A,
                                                  const ushort* __restrict__ Bw,
                                                  const float* __restrict__ bias,
                                                  float* __restrict__ C,
                                                  int M, int N, int K) {
  __shared__ ushort As[64 * 32];
  __shared__ ushort Bs[128 * 32];
  const int t = threadIdx.x;
  const int wid = t >> 6, lane = t & 63;
  const int quad = lane >> 4, l16 = lane & 15;
  const int bm = blockIdx.y * 64, bn = blockIdx.x * 128;
  const int wn = wid * 32;

  f32x4 acc[4][2];
  const f32x4 z = {0.f, 0.f, 0.f, 0.f};
#pragma unroll
  for (int i = 0; i < 4; ++i) { acc[i][0] = z; acc[i][1] = z; }

  const ushort* ag = A + (size_t)(bm + (t >> 2)) * K + ((t & 3) * 8);
  const ushort* bg = Bw + (size_t)(bn + (t >> 2)) * K + ((t & 3) * 8);
  ushort* asl = As + wid * 512;
  ushort* bsl = Bs + wid * 512;
  const size_t rowskip = (size_t)64 * K;

  for (int k0 = 0; k0 < K; k0 += 32) {
    glds16(ag + k0, asl);
    glds16(bg + k0, bsl);
    glds16(bg + k0 + rowskip, bsl + 2048);
    __syncthreads();
    bf16x8 af[4], bf[2];
#pragma unroll
    for (int i = 0; i < 4; ++i)
      af[i] = *(const bf16x8*)(As + (i * 16 + l16) * 32 + quad * 8);
#pragma unroll
    for (int j = 0; j < 2; ++j)
      bf[j] = *(const bf16x8*)(Bs + (wn + j * 16 + l16) * 32 + quad * 8);
#pragma unroll
    for (int i = 0; i < 4; ++i)
#pragma unroll
      for (int j = 0; j < 2; ++j)
        acc[i][j] = __builtin_amdgcn_mfma_f32_16x16x32_bf16(af[i], bf[j], acc[i][j], 0, 0, 0);
    __syncthreads();
  }

#pragma unroll
  for (int i = 0; i < 4; ++i)
#pragma unroll
    for (int j = 0; j < 2; ++j) {
      const int col = bn + wn + j * 16 + l16;
      const float bv = bias[col];
#pragma unroll
      for (int r = 0; r < 4; ++r) {
        const int row = bm + i * 16 + quad * 4 + r;
        C[(size_t)row * N + col] = acc[i][j][r] + bv;
      }
    }
}

// Per-(bh,chunk) KV sums via MFMA: mlocT[bh][c][e][f] = sum_s v[s][e]*k[s][f].
__global__ __launch_bounds__(256) void kv_local(const ushort* __restrict__ qkv,
                                                float* __restrict__ mlocT) {
  const int c = blockIdx.x, bh = blockIdx.y;
  const int b = bh >> 4, hd = bh & 15;
  const int t = threadIdx.x;
  const int wid = t >> 6, lane = t & 63;
  const int quad = lane >> 4, l16 = lane & 15;
  __shared__ ushort kT[64 * 136];  // [f:64][s:128] pad 8
  __shared__ ushort vT[64 * 136];  // [e:64][s:128] pad 8

  {
    const int row = t & 127;
    const int isv = t >> 7;
    const ushort* g = qkv + (size_t)(b * 2048 + c * 128 + row) * 3072 +
                      1024 + isv * 1024 + hd * 64;
    ushort tmp[64];
#pragma unroll
    for (int q = 0; q < 8; ++q) *(uint4*)(tmp + q * 8) = *(const uint4*)(g + q * 8);
    ushort* dst = isv ? vT : kT;
#pragma unroll
    for (int j = 0; j < 64; ++j) dst[j * 136 + row] = tmp[j];
  }
  __syncthreads();

  const f32x4 z = {0.f, 0.f, 0.f, 0.f};
  f32x4 acc[4];
#pragma unroll
  for (int ct = 0; ct < 4; ++ct) acc[ct] = z;
#pragma unroll
  for (int kc = 0; kc < 4; ++kc) {
    bf16x8 afr = *(const bf16x8*)(vT + (wid * 16 + l16) * 136 + kc * 32 + quad * 8);
#pragma unroll
    for (int ct = 0; ct < 4; ++ct) {
      bf16x8 bfr = *(const bf16x8*)(kT + (ct * 16 + l16) * 136 + kc * 32 + quad * 8);
      acc[ct] = __builtin_amdgcn_mfma_f32_16x16x32_bf16(afr, bfr, acc[ct], 0, 0, 0);
    }
  }

  float* outp = mlocT + ((size_t)bh * 16 + c) * 4096;
#pragma unroll
  for (int ct = 0; ct < 4; ++ct)
#pragma unroll
    for (int r = 0; r < 4; ++r)
      outp[(wid * 16 + quad * 4 + r) * 64 + ct * 16 + l16] = acc[ct][r];
}

// Exclusive prefix over chunks, parallel over 4096 (e,f) entries per bh.
__global__ __launch_bounds__(256) void kv_prefix(const float* __restrict__ mlocT,
                                                 ushort* __restrict__ statesT) {
  const int slice = blockIdx.x, bh = blockIdx.y;
  const int eidx = slice * 256 + threadIdx.x;
  float run = 0.f;
  for (int c = 0; c < 16; ++c) {
    const size_t idx = ((size_t)bh * 16 + c) * 4096 + eidx;
    statesT[idx] = f2bf(run);
    run += mlocT[idx];
  }
}

// Per-(bh,chunk): P = tril(Q K^T) ; Y = P V + Q S_prefix (state from statesT).
__global__ __launch_bounds__(256) void attn_chunk(const ushort* __restrict__ qkv,
                                                  const ushort* __restrict__ statesT,
                                                  ushort* __restrict__ yb) {
  const int c = blockIdx.x, bh = blockIdx.y;
  const int b = bh >> 4, hd = bh & 15;
  const int l0 = c * 128;
  const int t = threadIdx.x;
  const int wid = t >> 6, lane = t & 63;
  const int quad = lane >> 4, l16 = lane & 15;

  __shared__ ushort P[16384];  // [row][16B chunks] XOR-swizzled by row&7
  __shared__ ushort U[16384];
  ushort* Qs = U;              // [row:128][64] chunk^(row&7)
  ushort* Ks = U + 8192;
  ushort* vT = U;              // phase2: [e:64][s:128] stride 136
  ushort* sT = U + 8704;       // phase2: [e:64][f:64]  stride 72

  {  // zero P
    uint4 zz; zz.x = zz.y = zz.z = zz.w = 0u;
    uint4* p4 = (uint4*)P;
#pragma unroll
    for (int i = 0; i < 8; ++i) p4[i * 256 + t] = zz;
  }
  {  // stage Q,K swizzled
    const int kcs = ((lane & 7) ^ (lane >> 3)) * 8;
    const ushort* qg = qkv + (size_t)(b * 2048 + l0 + (t >> 3)) * 3072 + hd * 64 + kcs;
    ushort* ql = Qs + wid * 512;
    ushort* kl = Ks + wid * 512;
#pragma unroll
    for (int h2 = 0; h2 < 4; ++h2) {
      glds16(qg + (size_t)h2 * 32 * 3072, ql + h2 * 2048);
      glds16(qg + (size_t)h2 * 32 * 3072 + 1024, kl + h2 * 2048);
    }
  }
  __syncthreads();

  bf16x8 qf[2][2];
#pragma unroll
  for (int i = 0; i < 2; ++i)
#pragma unroll
    for (int kc = 0; kc < 2; ++kc)
      qf[i][kc] = *(const bf16x8*)(Qs + ((wid * 2 + i) * 16 + l16) * 64 +
                                   (((kc * 4 + quad) ^ (l16 & 7)) * 8));

  const f32x4 z4 = {0.f, 0.f, 0.f, 0.f};
  f32x4 pacc[2][8];
#pragma unroll
  for (int i = 0; i < 2; ++i)
#pragma unroll
    for (int j = 0; j < 8; ++j) pacc[i][j] = z4;

#pragma unroll
  for (int i = 0; i < 2; ++i) {
    const int rt = wid * 2 + i;
#pragma unroll
    for (int tj = 0; tj < 8; ++tj) {
      if (tj <= rt) {
#pragma unroll
        for (int kc = 0; kc < 2; ++kc) {
          bf16x8 kfr = *(const bf16x8*)(Ks + (tj * 16 + l16) * 64 +
                                        (((kc * 4 + quad) ^ (l16 & 7)) * 8));
          pacc[i][tj] = __builtin_amdgcn_mfma_f32_16x16x32_bf16(qf[i][kc], kfr, pacc[i][tj], 0, 0, 0);
        }
      }
    }
  }
  __syncthreads();

#pragma unroll
  for (int i = 0; i < 2; ++i) {
    const int rt = wid * 2 + i;
#pragma unroll
    for (int tj = 0; tj < 8; ++tj) {
      if (tj <= rt) {
#pragma unroll
        for (int r = 0; r < 4; ++r) {
          const int row = rt * 16 + quad * 4 + r;
          const int scol = tj * 16 + l16;
          const float v = (scol <= row) ? pacc[i][tj][r] : 0.f;
          P[row * 128 + (((scol >> 3) ^ (row & 7)) * 8) + (scol & 7)] = f2bf(v);
        }
      }
    }
  }
  {  // stage V transposed: vT[e][s], stride 136
    const int sstep = t >> 1, eb = (t & 1) * 32;
    const ushort* vg = qkv + (size_t)(b * 2048 + l0 + sstep) * 3072 + 2048 + hd * 64 + eb;
    ushort tmp[32];
    *(uint4*)(tmp + 0)  = *(const uint4*)(vg + 0);
    *(uint4*)(tmp + 8)  = *(const uint4*)(vg + 8);
    *(uint4*)(tmp + 16) = *(const uint4*)(vg + 16);
    *(uint4*)(tmp + 24) = *(const uint4*)(vg + 24);
#pragma unroll
    for (int j = 0; j < 32; ++j) vT[(eb + j) * 136 + sstep] = tmp[j];
  }
  {  // stage state: 2 coalesced uint4 per thread -> sT stride 72
    const ushort* sg = statesT + ((size_t)bh * 16 + c) * 4096;
#pragma unroll
    for (int h = 0; h < 2; ++h) {
      const int cc = h * 256 + t;
      uint4 d = *(const uint4*)(sg + cc * 8);
      *(uint4*)(sT + (cc >> 3) * 72 + (cc & 7) * 8) = d;
    }
  }
  __syncthreads();

  f32x4 yacc[2][4];
#pragma unroll
  for (int i = 0; i < 2; ++i)
#pragma unroll
    for (int j = 0; j < 4; ++j) yacc[i][j] = z4;

#pragma unroll
  for (int i = 0; i < 2; ++i) {
    const int rt = wid * 2 + i;
    const int kcmax = rt >> 1;
#pragma unroll
    for (int kc = 0; kc < 4; ++kc) {
      if (kc <= kcmax) {
        const int prow = rt * 16 + l16;
        bf16x8 pf;
        *(uint4*)&pf = *(const uint4*)(P + prow * 128 + (((kc * 4 + quad) ^ (prow & 7)) * 8));
#pragma unroll
        for (int ct = 0; ct < 4; ++ct) {
          bf16x8 vf = *(const bf16x8*)(vT + (ct * 16 + l16) * 136 + kc * 32 + quad * 8);
          yacc[i][ct] = __builtin_amdgcn_mfma_f32_16x16x32_bf16(pf, vf, yacc[i][ct], 0, 0, 0);
        }
      }
    }
#pragma unroll
    for (int kc = 0; kc < 2; ++kc) {
#pragma unroll
      for (int ct = 0; ct < 4; ++ct) {
        bf16x8 sf = *(const bf16x8*)(sT + (ct * 16 + l16) * 72 + kc * 32 + quad * 8);
        yacc[i][ct] = __builtin_amdgcn_mfma_f32_16x16x32_bf16(qf[i][kc], sf, yacc[i][ct], 0, 0, 0);
      }
    }
  }

#pragma unroll
  for (int i = 0; i < 2; ++i) {
    const int rt = wid * 2 + i;
#pragma unroll
    for (int ct = 0; ct < 4; ++ct) {
#pragma unroll
      for (int r = 0; r < 4; ++r) {
        const int row = rt * 16 + quad * 4 + r;
        const int e = ct * 16 + l16;
        yb[(size_t)(b * 2048 + l0 + row) * 1024 + hd * 64 + e] = f2bf(yacc[i][ct][r]);
      }
    }
  }
}

extern "C" void kernel_launch(void* const* d_in, const int* in_sizes, int n_in,
                              void* d_out, int out_size, void* d_ws, size_t ws_size,
                              hipStream_t stream) {
  const float* x  = (const float*)d_in[0];
  const float* Ww = (const float*)d_in[1];
  const float* Wb = (const float*)d_in[2];
  const float* Ow = (const float*)d_in[3];
  const float* Ob = (const float*)d_in[4];
  float* out = (float*)d_out;

  char* ws = (char*)d_ws;
  ushort* xb      = (ushort*)(ws);
  ushort* wqkvb   = (ushort*)(ws + (size_t)8  * 1024 * 1024);
  ushort* outwb   = (ushort*)(ws + (size_t)14 * 1024 * 1024);
  ushort* qkvb    = (ushort*)(ws + (size_t)16 * 1024 * 1024);
  float*  mlocT   = (float*) (ws + (size_t)40 * 1024 * 1024);
  ushort* statesT = (ushort*)(ws + (size_t)48 * 1024 * 1024);
  ushort* yb      = (ushort*)(ws + (size_t)52 * 1024 * 1024);

  cvt_all<<<8192, 256, 0, stream>>>(x, Ww, Ow, xb, wqkvb, outwb);
  // 256^2 tiles: grid = (3072/256)*(4096/256) = 192 blocks (1D, XCD-swizzled).
  gemm_bt8<true, true><<<dim3(192), 512, 0, stream>>>(xb, wqkvb, Wb, (void*)qkvb, 4096, 3072, 1024);
  kv_local<<<dim3(16, 32), 256, 0, stream>>>(qkvb, mlocT);
  kv_prefix<<<dim3(16, 32), 256, 0, stream>>>(mlocT, statesT);
  attn_chunk<<<dim3(16, 32), 256, 0, stream>>>(qkvb, statesT, yb);
  gemm_out64<<<dim3(8, 64), 256, 0, stream>>>(yb, outwb, Ob, out, 4096, 1024, 1024);
}